// Round 4
// baseline (699.994 us; speedup 1.0000x reference)
//
#include <hip/hip_runtime.h>

#define N 8192
#define D 64
#define JSPLIT 16
#define JSTEPS (N / 64 / JSPLIT)   // 8 J-tiles of 64 cols per block

typedef unsigned short ushort_t;
typedef __attribute__((ext_vector_type(8))) short bf16x8;
typedef __attribute__((ext_vector_type(4))) float f32x4;

// exp(cos/T) = exp(2*cos) = exp2(cos * 2/ln2). We fold sqrt(2/ln2) into BOTH
// normalized operands, so the MFMA dot product directly yields exp2's argument.
#define SQRT_2_OVER_LN2 1.6986436f

#if __has_builtin(__builtin_amdgcn_exp2f)
#define EXP2F(x) __builtin_amdgcn_exp2f(x)
#else
#define EXP2F(x) exp2f(x)
#endif

__device__ inline ushort_t f32_to_bf16(float f) {
    union { float f; unsigned u; } c; c.f = f;
    unsigned r = (c.u + 0x7FFFu + ((c.u >> 16) & 1u)) >> 16;
    return (ushort_t)r;
}

// ---------------- kernel 1: L2-normalize rows, scale, emit bf16 ---------
__global__ void normalize_kernel(const float* __restrict__ z_mp,
                                 const float* __restrict__ z_sc,
                                 ushort_t* __restrict__ zn) {
    int lane = threadIdx.x & 63;
    int row  = blockIdx.x * 4 + (threadIdx.x >> 6);
    const float* src = (row < N) ? z_mp : z_sc;
    int srow = row & (N - 1);
    float x = src[srow * D + lane];
    float s = x * x;
    #pragma unroll
    for (int m = 32; m; m >>= 1) s += __shfl_xor(s, m, 64);
    float n = sqrtf(s);
    float scale = SQRT_2_OVER_LN2 / fmaxf(n, 1e-12f);
    zn[row * D + lane] = f32_to_bf16(x * scale);
}

// ---------------- kernel 1b: compress pos (f32 0/1) -> bitmask ----------
// mask[row*128 + jw] bit j = (pos[row][jw*64+j] != 0). 8 MB total.
// Pure streaming: 4 coalesced dword loads + 4 ballots per wave per 1 KB.
__global__ __launch_bounds__(256) void compress_kernel(
        const float* __restrict__ pos,
        unsigned long long* __restrict__ mask) {
    int lane = threadIdx.x & 63;
    size_t wv = (size_t)blockIdx.x * 4 + (threadIdx.x >> 6);
    size_t nw = (size_t)gridDim.x * 4;
    const size_t units = (size_t)N * N / 256;   // 256 cols per wave-iter
    for (size_t u = wv; u < units; u += nw) {
        const float* base = pos + u * 256 + lane;
        unsigned long long w0 = __ballot(base[0]   > 0.5f);
        unsigned long long w1 = __ballot(base[64]  > 0.5f);
        unsigned long long w2 = __ballot(base[128] > 0.5f);
        unsigned long long w3 = __ballot(base[192] > 0.5f);
        if (lane == 0) {
            unsigned long long* mb = mask + u * 4;
            mb[0] = w0; mb[1] = w1; mb[2] = w2; mb[3] = w3;
        }
    }
}

// ---------------- kernel 2: tiled 4-pair similarity + row accumulation --
// 4 waves/block, wave w computes term (a=w>>1, b=w&1) on the same 64x64 tile.
// Column permutation: B-fragment c <- zn row (Jc + 4*lc + c), so a lane's 4
// output columns are the contiguous quad 4*lc..4*lc+3 -> pos bits are the
// nibble (mask_word >> 4*lc) & 0xF. Mask words + B-frags prefetched 1 jj ahead.
__global__ __launch_bounds__(256, 4) void contrast_main(
        const ushort_t* __restrict__ zn,
        const unsigned long long* __restrict__ mask,
        float* __restrict__ accum) {
    int lane = threadIdx.x & 63;
    int w    = threadIdx.x >> 6;       // wave 0..3
    int a = w >> 1, b = w & 1;         // 0=mp, 1=sc
    int term = (a == 0) ? (b == 0 ? 2 : 0) : (b == 0 ? 1 : 3);
    int rq = lane >> 4;                // 0..3
    int lc = lane & 15;                // 0..15
    unsigned sh = (unsigned)lc * 4;

    const ushort_t* Az = zn + a * (N * D);
    const ushort_t* Bz = zn + b * (N * D);

    int I0 = blockIdx.x * 64;
    int J0 = blockIdx.y * (N / JSPLIT);

    // A fragments: row = I0 + 16r + lc, k = s*32 + rq*8 .. +8 (held all loop)
    bf16x8 af[4][2];
    #pragma unroll
    for (int r = 0; r < 4; ++r)
        #pragma unroll
        for (int s = 0; s < 2; ++s)
            af[r][s] = *(const bf16x8*)(Az + (I0 + 16 * r + lc) * D + s * 32 + rq * 8);

    const ushort_t* bptr = Bz + ((size_t)(J0 + 4 * lc)) * D + rq * 8;
    const unsigned long long* mptr = mask + (size_t)(I0 + rq * 4) * (N / 64) + (J0 >> 6);

    bf16x8 bfc[4][2], bfn[4][2];
    unsigned nc[16], nn[16];

    float rs_acc[4][4], ps_acc[4][4];
    #pragma unroll
    for (int r = 0; r < 4; ++r)
        #pragma unroll
        for (int e = 0; e < 4; ++e) { rs_acc[r][e] = 0.0f; ps_acc[r][e] = 0.0f; }

    // prologue: B-frags + mask nibbles for jj=0
    #pragma unroll
    for (int c = 0; c < 4; ++c)
        #pragma unroll
        for (int s = 0; s < 2; ++s)
            bfc[c][s] = *(const bf16x8*)(bptr + c * D + s * 32);
    #pragma unroll
    for (int r = 0; r < 4; ++r)
        #pragma unroll
        for (int e = 0; e < 4; ++e)
            nc[r * 4 + e] = (unsigned)(mptr[(16 * r + e) * (N / 64)] >> sh) & 0xFu;

    #pragma unroll 2
    for (int jj = 0; jj < JSTEPS; ++jj) {
        if (jj + 1 < JSTEPS) {
            const ushort_t* bn = bptr + 64 * D;
            #pragma unroll
            for (int c = 0; c < 4; ++c)
                #pragma unroll
                for (int s = 0; s < 2; ++s)
                    bfn[c][s] = *(const bf16x8*)(bn + c * D + s * 32);
            #pragma unroll
            for (int r = 0; r < 4; ++r)
                #pragma unroll
                for (int e = 0; e < 4; ++e)
                    nn[r * 4 + e] = (unsigned)(mptr[(16 * r + e) * (N / 64) + jj + 1] >> sh) & 0xFu;
        }

        #pragma unroll
        for (int r = 0; r < 4; ++r) {
            f32x4 acc[4];
            #pragma unroll
            for (int c = 0; c < 4; ++c) acc[c] = (f32x4){0.f, 0.f, 0.f, 0.f};
            #pragma unroll
            for (int s = 0; s < 2; ++s)
                #pragma unroll
                for (int c = 0; c < 4; ++c)
                    acc[c] = __builtin_amdgcn_mfma_f32_16x16x32_bf16(
                        af[r][s], bfc[c][s], acc[c], 0, 0, 0);

            #pragma unroll
            for (int e = 0; e < 4; ++e) {
                unsigned nib = nc[r * 4 + e];
                float rs = rs_acc[r][e], ps = ps_acc[r][e];
                #pragma unroll
                for (int c = 0; c < 4; ++c) {
                    float eV = EXP2F(acc[c][e]);           // arg pre-scaled
                    rs += eV;
                    ps = fmaf((float)((nib >> c) & 1u), eV, ps);
                }
                rs_acc[r][e] = rs; ps_acc[r][e] = ps;
            }
        }

        bptr += 64 * D;
        #pragma unroll
        for (int c = 0; c < 4; ++c)
            #pragma unroll
            for (int s = 0; s < 2; ++s)
                bfc[c][s] = bfn[c][s];
        #pragma unroll
        for (int i = 0; i < 16; ++i) nc[i] = nn[i];
    }

    // butterfly-reduce across the 16 lanes sharing each row (lane bits 0..3)
    #pragma unroll
    for (int r = 0; r < 4; ++r)
        #pragma unroll
        for (int e = 0; e < 4; ++e) {
            float rs = rs_acc[r][e], ps = ps_acc[r][e];
            #pragma unroll
            for (int m = 1; m < 16; m <<= 1) {
                rs += __shfl_xor(rs, m, 64);
                ps += __shfl_xor(ps, m, 64);
            }
            rs_acc[r][e] = rs; ps_acc[r][e] = ps;
        }

    if (lc == 0) {
        #pragma unroll
        for (int r = 0; r < 4; ++r)
            #pragma unroll
            for (int e = 0; e < 4; ++e) {
                int gi = I0 + 16 * r + rq * 4 + e;
                atomicAdd(&accum[term * 2 * N + gi],     rs_acc[r][e]);
                atomicAdd(&accum[term * 2 * N + N + gi], ps_acc[r][e]);
            }
    }
}

// ---------------- kernel 3: final loss reduction ------------------------
__global__ void finalize_kernel(const float* __restrict__ accum,
                                float* __restrict__ out) {
    __shared__ float red[256];
    float local = 0.0f;
    for (int i = threadIdx.x; i < N; i += 256) {
        float s = 0.0f;
        #pragma unroll
        for (int t = 0; t < 4; ++t) {
            float rs = accum[t * 2 * N + i];
            float ps = accum[t * 2 * N + N + i];
            s += logf(ps / (rs + 1e-8f));
        }
        local += s;
    }
    red[threadIdx.x] = local;
    __syncthreads();
    for (int m = 128; m; m >>= 1) {
        if (threadIdx.x < m) red[threadIdx.x] += red[threadIdx.x + m];
        __syncthreads();
    }
    if (threadIdx.x == 0) out[0] = -red[0] / (float)N;
}

extern "C" void kernel_launch(void* const* d_in, const int* in_sizes, int n_in,
                              void* d_out, int out_size, void* d_ws, size_t ws_size,
                              hipStream_t stream) {
    const float* z_mp = (const float*)d_in[0];
    const float* z_sc = (const float*)d_in[1];
    const float* pos  = (const float*)d_in[2];
    float* out = (float*)d_out;

    ushort_t* zn = (ushort_t*)d_ws;                                       // 2 MB
    float* accum = (float*)((char*)d_ws + (size_t)2 * N * D * sizeof(ushort_t));   // 256 KB
    unsigned long long* mask = (unsigned long long*)((char*)accum
                               + (size_t)4 * 2 * N * sizeof(float));      // 8 MB

    hipMemsetAsync(accum, 0, (size_t)4 * 2 * N * sizeof(float), stream);
    normalize_kernel<<<(2 * N) / 4, 256, 0, stream>>>(z_mp, z_sc, zn);
    compress_kernel<<<2048, 256, 0, stream>>>(pos, mask);
    dim3 grid(N / 64, JSPLIT);
    contrast_main<<<grid, 256, 0, stream>>>(zn, mask, accum);
    finalize_kernel<<<1, 256, 0, stream>>>(accum, out);
}

// Round 5
// 215.815 us; speedup vs baseline: 3.2435x; 3.2435x over previous
//
#include <hip/hip_runtime.h>

#define N 8192
#define D 64
#define JSPLIT 16
#define JSTEPS (N / 64 / JSPLIT)   // 8 J-tiles of 64 cols per block

typedef unsigned short ushort_t;
typedef __attribute__((ext_vector_type(8))) short bf16x8;
typedef __attribute__((ext_vector_type(4))) float f32x4;

// exp(cos/T) = exp(2*cos) = exp2(cos * 2/ln2). sqrt(2/ln2) is folded into BOTH
// normalized operands, so the MFMA dot product directly yields exp2's argument.
#define SQRT_2_OVER_LN2 1.6986436f

#if __has_builtin(__builtin_amdgcn_exp2f)
#define EXP2F(x) __builtin_amdgcn_exp2f(x)
#else
#define EXP2F(x) exp2f(x)
#endif

__device__ inline ushort_t f32_to_bf16(float f) {
    union { float f; unsigned u; } c; c.f = f;
    unsigned r = (c.u + 0x7FFFu + ((c.u >> 16) & 1u)) >> 16;
    return (ushort_t)r;
}

// ---------------- kernel 1: L2-normalize rows, scale, emit bf16 ---------
__global__ void normalize_kernel(const float* __restrict__ z_mp,
                                 const float* __restrict__ z_sc,
                                 ushort_t* __restrict__ zn) {
    int lane = threadIdx.x & 63;
    int row  = blockIdx.x * 4 + (threadIdx.x >> 6);
    const float* src = (row < N) ? z_mp : z_sc;
    int srow = row & (N - 1);
    float x = src[srow * D + lane];
    float s = x * x;
    #pragma unroll
    for (int m = 32; m; m >>= 1) s += __shfl_xor(s, m, 64);
    float n = sqrtf(s);
    float scale = SQRT_2_OVER_LN2 / fmaxf(n, 1e-12f);
    zn[row * D + lane] = f32_to_bf16(x * scale);
}

// ---------------- kernel 1b: compress pos (f32 0/1) -> bitmask ----------
// mask[row*128 + jw] bit j = (pos[row][jw*64+j] != 0). 8 MB total.
__global__ __launch_bounds__(256) void compress_kernel(
        const float* __restrict__ pos,
        unsigned long long* __restrict__ mask) {
    int lane = threadIdx.x & 63;
    size_t wv = (size_t)blockIdx.x * 4 + (threadIdx.x >> 6);
    size_t nw = (size_t)gridDim.x * 4;
    const size_t units = (size_t)N * N / 256;   // 256 cols per wave-iter
    for (size_t u = wv; u < units; u += nw) {
        const float* base = pos + u * 256 + lane;
        unsigned long long w0 = __ballot(base[0]   > 0.5f);
        unsigned long long w1 = __ballot(base[64]  > 0.5f);
        unsigned long long w2 = __ballot(base[128] > 0.5f);
        unsigned long long w3 = __ballot(base[192] > 0.5f);
        if (lane == 0) {
            unsigned long long* mb = mask + u * 4;
            mb[0] = w0; mb[1] = w1; mb[2] = w2; mb[3] = w3;
        }
    }
}

// ---------------- kernel 2: tiled 4-pair similarity + row accumulation --
// 4 waves/block, wave w computes term (a=w>>1, b=w&1) on the same 64x64 tile.
// Column permutation: B-fragment c <- zn row (Jc + 4*lc + c), so a lane's 4
// output columns are the contiguous quad 4*lc..4*lc+3 -> pos bits are the
// nibble (mask_word >> 4*lc) & 0xF. Mask words are wave-uniform addresses
// (L1 broadcast, 4 KB per block total).
__global__ __launch_bounds__(256, 2) void contrast_main(
        const ushort_t* __restrict__ zn,
        const unsigned long long* __restrict__ mask,
        float* __restrict__ accum) {
    int lane = threadIdx.x & 63;
    int w    = threadIdx.x >> 6;       // wave 0..3
    int a = w >> 1, b = w & 1;         // 0=mp, 1=sc
    int term = (a == 0) ? (b == 0 ? 2 : 0) : (b == 0 ? 1 : 3);
    int rq = lane >> 4;                // 0..3
    int lc = lane & 15;                // 0..15
    unsigned sh = (unsigned)lc * 4;

    const ushort_t* Az = zn + a * (N * D);
    const ushort_t* Bz = zn + b * (N * D);

    int I0 = blockIdx.x * 64;
    int J0 = blockIdx.y * (N / JSPLIT);

    // A fragments: row = I0 + 16r + lc, k = s*32 + rq*8 .. +8 (held all loop)
    bf16x8 af[4][2];
    #pragma unroll
    for (int r = 0; r < 4; ++r)
        #pragma unroll
        for (int s = 0; s < 2; ++s)
            af[r][s] = *(const bf16x8*)(Az + (I0 + 16 * r + lc) * D + s * 32 + rq * 8);

    const ushort_t* bptr = Bz + ((size_t)(J0 + 4 * lc)) * D + rq * 8;
    const unsigned long long* mptr = mask + (size_t)(I0 + rq * 4) * (N / 64) + (J0 >> 6);

    float rs_acc[4][4], ps_acc[4][4];
    #pragma unroll
    for (int r = 0; r < 4; ++r)
        #pragma unroll
        for (int e = 0; e < 4; ++e) { rs_acc[r][e] = 0.0f; ps_acc[r][e] = 0.0f; }

    #pragma unroll 1
    for (int jj = 0; jj < JSTEPS; ++jj) {
        // B fragments for this jj (single-buffered; TLP hides L2 latency)
        bf16x8 bf[4][2];
        #pragma unroll
        for (int c = 0; c < 4; ++c)
            #pragma unroll
            for (int s = 0; s < 2; ++s)
                bf[c][s] = *(const bf16x8*)(bptr + c * D + s * 32);

        #pragma unroll
        for (int r = 0; r < 4; ++r) {
            // mask words for this r's 4 rows (issued before MFMA, used after)
            unsigned long long mw[4];
            #pragma unroll
            for (int e = 0; e < 4; ++e)
                mw[e] = mptr[(size_t)(16 * r + e) * (N / 64) + jj];

            f32x4 acc[4];
            #pragma unroll
            for (int c = 0; c < 4; ++c) acc[c] = (f32x4){0.f, 0.f, 0.f, 0.f};
            #pragma unroll
            for (int s = 0; s < 2; ++s)
                #pragma unroll
                for (int c = 0; c < 4; ++c)
                    acc[c] = __builtin_amdgcn_mfma_f32_16x16x32_bf16(
                        af[r][s], bf[c][s], acc[c], 0, 0, 0);

            #pragma unroll
            for (int e = 0; e < 4; ++e) {
                unsigned nib = (unsigned)(mw[e] >> sh) & 0xFu;
                float rs = rs_acc[r][e], ps = ps_acc[r][e];
                #pragma unroll
                for (int c = 0; c < 4; ++c) {
                    float eV = EXP2F(acc[c][e]);           // arg pre-scaled
                    rs += eV;
                    ps = fmaf((float)((nib >> c) & 1u), eV, ps);
                }
                rs_acc[r][e] = rs; ps_acc[r][e] = ps;
            }
        }
        bptr += 64 * D;
    }

    // butterfly-reduce across the 16 lanes sharing each row (lane bits 0..3)
    #pragma unroll
    for (int r = 0; r < 4; ++r)
        #pragma unroll
        for (int e = 0; e < 4; ++e) {
            float rs = rs_acc[r][e], ps = ps_acc[r][e];
            #pragma unroll
            for (int m = 1; m < 16; m <<= 1) {
                rs += __shfl_xor(rs, m, 64);
                ps += __shfl_xor(ps, m, 64);
            }
            rs_acc[r][e] = rs; ps_acc[r][e] = ps;
        }

    if (lc == 0) {
        #pragma unroll
        for (int r = 0; r < 4; ++r)
            #pragma unroll
            for (int e = 0; e < 4; ++e) {
                int gi = I0 + 16 * r + rq * 4 + e;
                atomicAdd(&accum[term * 2 * N + gi],     rs_acc[r][e]);
                atomicAdd(&accum[term * 2 * N + N + gi], ps_acc[r][e]);
            }
    }
}

// ---------------- kernel 3: final loss reduction ------------------------
__global__ void finalize_kernel(const float* __restrict__ accum,
                                float* __restrict__ out) {
    __shared__ float red[256];
    float local = 0.0f;
    for (int i = threadIdx.x; i < N; i += 256) {
        float s = 0.0f;
        #pragma unroll
        for (int t = 0; t < 4; ++t) {
            float rs = accum[t * 2 * N + i];
            float ps = accum[t * 2 * N + N + i];
            s += logf(ps / (rs + 1e-8f));
        }
        local += s;
    }
    red[threadIdx.x] = local;
    __syncthreads();
    for (int m = 128; m; m >>= 1) {
        if (threadIdx.x < m) red[threadIdx.x] += red[threadIdx.x + m];
        __syncthreads();
    }
    if (threadIdx.x == 0) out[0] = -red[0] / (float)N;
}

extern "C" void kernel_launch(void* const* d_in, const int* in_sizes, int n_in,
                              void* d_out, int out_size, void* d_ws, size_t ws_size,
                              hipStream_t stream) {
    const float* z_mp = (const float*)d_in[0];
    const float* z_sc = (const float*)d_in[1];
    const float* pos  = (const float*)d_in[2];
    float* out = (float*)d_out;

    ushort_t* zn = (ushort_t*)d_ws;                                       // 2 MB
    float* accum = (float*)((char*)d_ws + (size_t)2 * N * D * sizeof(ushort_t));   // 256 KB
    unsigned long long* mask = (unsigned long long*)((char*)accum
                               + (size_t)4 * 2 * N * sizeof(float));      // 8 MB

    hipMemsetAsync(accum, 0, (size_t)4 * 2 * N * sizeof(float), stream);
    normalize_kernel<<<(2 * N) / 4, 256, 0, stream>>>(z_mp, z_sc, zn);
    compress_kernel<<<2048, 256, 0, stream>>>(pos, mask);
    dim3 grid(N / 64, JSPLIT);
    contrast_main<<<grid, 256, 0, stream>>>(zn, mask, accum);
    finalize_kernel<<<1, 256, 0, stream>>>(accum, out);
}

// Round 6
// 212.720 us; speedup vs baseline: 3.2907x; 1.0145x over previous
//
#include <hip/hip_runtime.h>

#define N 8192
#define D 64
#define JSPLIT 16
#define JSTEPS (N / 64 / JSPLIT)   // 8 J-tiles of 64 cols per block

typedef unsigned short ushort_t;
typedef __attribute__((ext_vector_type(8))) short bf16x8;
typedef __attribute__((ext_vector_type(4))) float f32x4;

// exp(cos/T) = exp(2*cos) = exp2(cos * 2/ln2). sqrt(2/ln2) is folded into BOTH
// normalized operands, so the MFMA dot product directly yields exp2's argument.
#define SQRT_2_OVER_LN2 1.6986436f

// Single-instruction exp2: args are bounded (|x| <= 2.9), no edge cases needed.
__device__ inline float fast_exp2(float x) {
    float r;
    asm("v_exp_f32 %0, %1" : "=v"(r) : "v"(x));
    return r;
}

__device__ inline ushort_t f32_to_bf16(float f) {
    union { float f; unsigned u; } c; c.f = f;
    unsigned r = (c.u + 0x7FFFu + ((c.u >> 16) & 1u)) >> 16;
    return (ushort_t)r;
}

// ---------------- kernel 1: L2-normalize rows, scale, emit bf16 ---------
// Also zeroes the 64K-float accum buffer (blocks 0..255), replacing the
// graph-captured hipMemsetAsync which showed a 156us anomaly.
__global__ void normalize_kernel(const float* __restrict__ z_mp,
                                 const float* __restrict__ z_sc,
                                 ushort_t* __restrict__ zn,
                                 float* __restrict__ accum) {
    if (blockIdx.x < 256) accum[blockIdx.x * 256 + threadIdx.x] = 0.0f;
    int lane = threadIdx.x & 63;
    int row  = blockIdx.x * 4 + (threadIdx.x >> 6);
    const float* src = (row < N) ? z_mp : z_sc;
    int srow = row & (N - 1);
    float x = src[srow * D + lane];
    float s = x * x;
    #pragma unroll
    for (int m = 32; m; m >>= 1) s += __shfl_xor(s, m, 64);
    float n = sqrtf(s);
    float scale = SQRT_2_OVER_LN2 / fmaxf(n, 1e-12f);
    zn[row * D + lane] = f32_to_bf16(x * scale);
}

// ---------------- kernel 1b: compress pos (f32 0/1) -> bitmask ----------
// mask[row*128 + jw] bit j = (pos[row][jw*64+j] != 0). 8 MB total.
__global__ __launch_bounds__(256) void compress_kernel(
        const float* __restrict__ pos,
        unsigned long long* __restrict__ mask) {
    int lane = threadIdx.x & 63;
    size_t wv = (size_t)blockIdx.x * 4 + (threadIdx.x >> 6);
    size_t nw = (size_t)gridDim.x * 4;
    const size_t units = (size_t)N * N / 256;   // 256 cols per wave-iter
    for (size_t u = wv; u < units; u += nw) {
        const float* base = pos + u * 256 + lane;
        unsigned long long w0 = __ballot(base[0]   > 0.5f);
        unsigned long long w1 = __ballot(base[64]  > 0.5f);
        unsigned long long w2 = __ballot(base[128] > 0.5f);
        unsigned long long w3 = __ballot(base[192] > 0.5f);
        if (lane == 0) {
            unsigned long long* mb = mask + u * 4;
            mb[0] = w0; mb[1] = w1; mb[2] = w2; mb[3] = w3;
        }
    }
}

// ---------------- kernel 2: tiled 4-pair similarity + row accumulation --
// 4 waves/block, wave w computes term (a=w>>1, b=w&1) on the same 64x64 tile.
// Column permutation: B-fragment c <- zn row (Jc + 4*lc + c), so a lane's 4
// output columns are the contiguous quad 4*lc..4*lc+3 -> pos bits are one
// nibble of a u32 mask word. B-frags double-buffered (prefetch jj+1 during
// jj's compute). Mask words loaded per r-subtile as u32 (4 live VGPRs).
__global__ __launch_bounds__(256, 3) void contrast_main(
        const ushort_t* __restrict__ zn,
        const unsigned* __restrict__ mask32,
        float* __restrict__ accum) {
    int lane = threadIdx.x & 63;
    int w    = threadIdx.x >> 6;       // wave 0..3
    int a = w >> 1, b = w & 1;         // 0=mp, 1=sc
    int term = (a == 0) ? (b == 0 ? 2 : 0) : (b == 0 ? 1 : 3);
    int rq = lane >> 4;                // 0..3
    int lc = lane & 15;                // 0..15
    unsigned sh = (unsigned)(lc & 7) * 4;   // nibble shift within u32

    const ushort_t* Az = zn + a * (N * D);
    const ushort_t* Bz = zn + b * (N * D);

    int I0 = blockIdx.x * 64;
    int J0 = blockIdx.y * (N / JSPLIT);

    // A fragments: row = I0 + 16r + lc, k = s*32 + rq*8 .. +8 (held all loop)
    bf16x8 af[4][2];
    #pragma unroll
    for (int r = 0; r < 4; ++r)
        #pragma unroll
        for (int s = 0; s < 2; ++s)
            af[r][s] = *(const bf16x8*)(Az + (I0 + 16 * r + lc) * D + s * 32 + rq * 8);

    const ushort_t* bptr = Bz + ((size_t)(J0 + 4 * lc)) * D + rq * 8;
    // u32 view of mask: row stride N/32=256 words; 64 cols = 2 words per jj.
    const unsigned* mrow = mask32 + (size_t)(I0 + rq * 4) * (N / 32)
                                  + (J0 >> 5) + (lc >> 3);

    float rs_acc[4][4], ps_acc[4][4];
    #pragma unroll
    for (int r = 0; r < 4; ++r)
        #pragma unroll
        for (int e = 0; e < 4; ++e) { rs_acc[r][e] = 0.0f; ps_acc[r][e] = 0.0f; }

    bf16x8 bfc[4][2], bfn[4][2];
    #pragma unroll
    for (int c = 0; c < 4; ++c)
        #pragma unroll
        for (int s = 0; s < 2; ++s)
            bfc[c][s] = *(const bf16x8*)(bptr + c * D + s * 32);

    #pragma unroll 1
    for (int jj = 0; jj < JSTEPS; ++jj) {
        if (jj + 1 < JSTEPS) {
            const ushort_t* bn = bptr + 64 * D;
            #pragma unroll
            for (int c = 0; c < 4; ++c)
                #pragma unroll
                for (int s = 0; s < 2; ++s)
                    bfn[c][s] = *(const bf16x8*)(bn + c * D + s * 32);
        }

        #pragma unroll
        for (int r = 0; r < 4; ++r) {
            // mask u32 for this r's 4 rows (issued before MFMA, used after)
            unsigned mw[4];
            #pragma unroll
            for (int e = 0; e < 4; ++e)
                mw[e] = mrow[(size_t)(16 * r + e) * (N / 32) + jj * 2];

            f32x4 acc[4];
            #pragma unroll
            for (int c = 0; c < 4; ++c) acc[c] = (f32x4){0.f, 0.f, 0.f, 0.f};
            #pragma unroll
            for (int s = 0; s < 2; ++s)
                #pragma unroll
                for (int c = 0; c < 4; ++c)
                    acc[c] = __builtin_amdgcn_mfma_f32_16x16x32_bf16(
                        af[r][s], bfc[c][s], acc[c], 0, 0, 0);

            #pragma unroll
            for (int e = 0; e < 4; ++e) {
                unsigned nib = (mw[e] >> sh) & 0xFu;
                float rs = rs_acc[r][e], ps = ps_acc[r][e];
                #pragma unroll
                for (int c = 0; c < 4; ++c) {
                    float eV = fast_exp2(acc[c][e]);       // arg pre-scaled
                    rs += eV;
                    ps = fmaf((float)((nib >> c) & 1u), eV, ps);
                }
                rs_acc[r][e] = rs; ps_acc[r][e] = ps;
            }
        }

        bptr += 64 * D;
        #pragma unroll
        for (int c = 0; c < 4; ++c)
            #pragma unroll
            for (int s = 0; s < 2; ++s)
                bfc[c][s] = bfn[c][s];
    }

    // butterfly-reduce across the 16 lanes sharing each row (lane bits 0..3)
    #pragma unroll
    for (int r = 0; r < 4; ++r)
        #pragma unroll
        for (int e = 0; e < 4; ++e) {
            float rs = rs_acc[r][e], ps = ps_acc[r][e];
            #pragma unroll
            for (int m = 1; m < 16; m <<= 1) {
                rs += __shfl_xor(rs, m, 64);
                ps += __shfl_xor(ps, m, 64);
            }
            rs_acc[r][e] = rs; ps_acc[r][e] = ps;
        }

    if (lc == 0) {
        #pragma unroll
        for (int r = 0; r < 4; ++r)
            #pragma unroll
            for (int e = 0; e < 4; ++e) {
                int gi = I0 + 16 * r + rq * 4 + e;
                atomicAdd(&accum[term * 2 * N + gi],     rs_acc[r][e]);
                atomicAdd(&accum[term * 2 * N + N + gi], ps_acc[r][e]);
            }
    }
}

// ---------------- kernel 3: final loss reduction ------------------------
__global__ void finalize_kernel(const float* __restrict__ accum,
                                float* __restrict__ out) {
    __shared__ float red[256];
    float local = 0.0f;
    for (int i = threadIdx.x; i < N; i += 256) {
        float s = 0.0f;
        #pragma unroll
        for (int t = 0; t < 4; ++t) {
            float rs = accum[t * 2 * N + i];
            float ps = accum[t * 2 * N + N + i];
            s += logf(ps / (rs + 1e-8f));
        }
        local += s;
    }
    red[threadIdx.x] = local;
    __syncthreads();
    for (int m = 128; m; m >>= 1) {
        if (threadIdx.x < m) red[threadIdx.x] += red[threadIdx.x + m];
        __syncthreads();
    }
    if (threadIdx.x == 0) out[0] = -red[0] / (float)N;
}

extern "C" void kernel_launch(void* const* d_in, const int* in_sizes, int n_in,
                              void* d_out, int out_size, void* d_ws, size_t ws_size,
                              hipStream_t stream) {
    const float* z_mp = (const float*)d_in[0];
    const float* z_sc = (const float*)d_in[1];
    const float* pos  = (const float*)d_in[2];
    float* out = (float*)d_out;

    ushort_t* zn = (ushort_t*)d_ws;                                       // 2 MB
    float* accum = (float*)((char*)d_ws + (size_t)2 * N * D * sizeof(ushort_t));   // 256 KB
    unsigned long long* mask = (unsigned long long*)((char*)accum
                               + (size_t)4 * 2 * N * sizeof(float));      // 8 MB

    normalize_kernel<<<(2 * N) / 4, 256, 0, stream>>>(z_mp, z_sc, zn, accum);
    compress_kernel<<<2048, 256, 0, stream>>>(pos, mask);
    dim3 grid(N / 64, JSPLIT);
    contrast_main<<<grid, 256, 0, stream>>>(zn, (const unsigned*)mask, accum);
    finalize_kernel<<<1, 256, 0, stream>>>(accum, out);
}